// Round 2
// 399.673 us; speedup vs baseline: 1.1368x; 1.1368x over previous
//
#include <hip/hip_runtime.h>
#include <math.h>

#define TT 2048   // tokens
#define HH 1024   // hidden
#define EE 8      // experts
#define II 2048   // intermediate
#define N1 4096   // 2*II
#define ALPHA 1.702f
#define LIMIT 7.0f

typedef __attribute__((ext_vector_type(8))) short short8;
typedef __attribute__((ext_vector_type(4))) float floatx4;
typedef __attribute__((ext_vector_type(4))) unsigned int uintx4;

__device__ __forceinline__ short f2bf(float f) {
  union { float f; unsigned u; } v; v.f = f;
  unsigned r = (v.u + 0x7fffu + ((v.u >> 16) & 1u)) >> 16;
  return (short)r;
}
__device__ __forceinline__ float bf2f(unsigned short s) {
  union { unsigned u; float f; } v; v.u = ((unsigned)s) << 16;
  return v.f;
}
// 2x f32 -> packed bf16 (RNE) in one instruction
__device__ __forceinline__ unsigned cvt2(float lo, float hi) {
  unsigned r;
  asm("v_cvt_pk_bf16_f32 %0, %1, %2" : "=v"(r) : "v"(lo), "v"(hi));
  return r;
}

// ---------------- router: logits -> softmax -> top2 ----------------
__global__ __launch_bounds__(256) void router_kernel(
    const float* __restrict__ x, const float* __restrict__ rw,
    const float* __restrict__ rb, int* __restrict__ topk_idx,
    float* __restrict__ topk_w) {
  const int t = blockIdx.x;
  const float* xr = x + (size_t)t * HH;
  const int lane = threadIdx.x & 63;
  const int wave = threadIdx.x >> 6;
  float xv[16];
#pragma unroll
  for (int i = 0; i < 16; i++) xv[i] = xr[lane + i * 64];
  __shared__ float logits[EE];
#pragma unroll
  for (int ee = 0; ee < 2; ee++) {
    const int e = wave * 2 + ee;
    const float* wr = rw + (size_t)e * HH;
    float s = 0.f;
#pragma unroll
    for (int i = 0; i < 16; i++) s += xv[i] * wr[lane + i * 64];
#pragma unroll
    for (int off = 32; off > 0; off >>= 1) s += __shfl_down(s, off, 64);
    if (lane == 0) logits[e] = s + rb[e];
  }
  __syncthreads();
  if (threadIdx.x == 0) {
    float l[EE], sc[EE];
    float mx = -3.4e38f;
    for (int i = 0; i < EE; i++) { l[i] = logits[i]; mx = fmaxf(mx, l[i]); }
    float sum = 0.f;
    for (int i = 0; i < EE; i++) { sc[i] = expf(l[i] - mx); sum += sc[i]; }
    const float inv = 1.f / sum;
    int i0 = 0;
    for (int i = 1; i < EE; i++) if (sc[i] > sc[i0]) i0 = i;
    int i1 = (i0 == 0) ? 1 : 0;
    for (int i = 0; i < EE; i++) if (i != i0 && sc[i] > sc[i1]) i1 = i;
    topk_idx[t * 2 + 0] = i0;
    topk_idx[t * 2 + 1] = i1;
    topk_w[t * 2 + 0] = sc[i0] * inv;
    topk_w[t * 2 + 1] = sc[i1] * inv;
  }
}

// ---------------- token->expert compaction ----------------
__global__ void assign_kernel(const int* __restrict__ topk_idx,
                              int* __restrict__ counts, int* __restrict__ rows) {
  const int id = blockIdx.x * blockDim.x + threadIdx.x;
  if (id >= TT * 2) return;
  const int e = topk_idx[id];
  const int slot = atomicAdd(&counts[e], 1);
  rows[e * TT + slot] = id;  // entry = t*2 + k
}

// ---------------- GEMM1: gathered x (f32->bf16) x gate_up_proj[e] -> gu (bf16) --
// 512 threads = 8 waves (2M x 4N), 128x128 tile, register double-buffered.
__global__ __launch_bounds__(512, 4) void gemm_gu(
    const float* __restrict__ x, const float* __restrict__ gup,
    const float* __restrict__ gub, const int* __restrict__ counts,
    const int* __restrict__ rows, unsigned short* __restrict__ gu) {
  const int e = blockIdx.z, mtile = blockIdx.y, ntile = blockIdx.x;
  const int count = counts[e];
  if (mtile * 128 >= count) return;
  const int* rl = rows + e * TT + mtile * 128;
  __shared__ short As[128][40];  // [m][k], +8 pad -> 2-way (free) b128 banks
  __shared__ short Bs[128][40];  // [n][k]
  const int tid = threadIdx.x;
  const int lane = tid & 63, wave = tid >> 6;
  const int wm = (wave & 1) << 6, wn = (wave >> 1) << 5;
  const int quad = lane >> 4, r16 = lane & 15;

  // A staging: 1 thread = 1 row-chunk of 8 f32 (16B bf16)
  const int arow = tid >> 2, akoct = tid & 3;
  const int cr = (mtile * 128 + arow < count) ? arow : (count - 1 - mtile * 128);
  const float* ap = x + (size_t)(rl[cr] >> 1) * HH + akoct * 8;

  // B staging: 1 thread = 8 strided f32 of one column
  const int bn = tid & 127, bko = tid >> 7;  // bko in 0..3
  const float* bp = gup + (size_t)e * HH * N1 + (size_t)bko * 8 * N1 + ntile * 128 + bn;

  floatx4 acc[4][2] = {};

  // prologue: prefetch k-tile 0 into registers
  float4 va0 = ((const float4*)ap)[0];
  float4 va1 = ((const float4*)ap)[1];
  float vb[8];
#pragma unroll
  for (int j = 0; j < 8; j++) vb[j] = bp[(size_t)j * N1];
  ap += 32;
  bp += (size_t)32 * N1;

  for (int k0 = 0; k0 < HH; k0 += 32) {
    __syncthreads();  // previous tile's LDS reads done
    uintx4 aw, bw;
    aw[0] = cvt2(va0.x, va0.y); aw[1] = cvt2(va0.z, va0.w);
    aw[2] = cvt2(va1.x, va1.y); aw[3] = cvt2(va1.z, va1.w);
    bw[0] = cvt2(vb[0], vb[1]); bw[1] = cvt2(vb[2], vb[3]);
    bw[2] = cvt2(vb[4], vb[5]); bw[3] = cvt2(vb[6], vb[7]);
    *(uintx4*)&As[arow][akoct * 8] = aw;
    *(uintx4*)&Bs[bn][bko * 8] = bw;
    if (k0 + 32 < HH) {  // issue next tile's loads; latency hides under MFMA
      va0 = ((const float4*)ap)[0];
      va1 = ((const float4*)ap)[1];
#pragma unroll
      for (int j = 0; j < 8; j++) vb[j] = bp[(size_t)j * N1];
      ap += 32;
      bp += (size_t)32 * N1;
    }
    __syncthreads();
    short8 af[4], bf_[2];
#pragma unroll
    for (int i = 0; i < 4; i++)
      af[i] = *(const short8*)&As[wm + i * 16 + r16][quad * 8];
#pragma unroll
    for (int j = 0; j < 2; j++)
      bf_[j] = *(const short8*)&Bs[wn + j * 16 + r16][quad * 8];
#pragma unroll
    for (int i = 0; i < 4; i++)
#pragma unroll
      for (int j = 0; j < 2; j++)
        acc[i][j] = __builtin_amdgcn_mfma_f32_16x16x32_bf16(af[i], bf_[j], acc[i][j], 0, 0, 0);
  }
#pragma unroll
  for (int i = 0; i < 4; i++) {
#pragma unroll
    for (int reg = 0; reg < 4; reg++) {
      const int rrow = wm + i * 16 + quad * 4 + reg;
      if (mtile * 128 + rrow < count) {
        const int ent = rl[rrow];
        unsigned short* orow = gu + (size_t)ent * N1 + ntile * 128;
#pragma unroll
        for (int j = 0; j < 2; j++) {
          const int c = wn + j * 16 + r16;
          const float v = acc[i][j][reg] + gub[e * N1 + ntile * 128 + c];
          orow[c] = (unsigned short)f2bf(v);
        }
      }
    }
  }
}

// ---------------- activation: gu -> act (vectorized x8) ----------------
__global__ void act_kernel(const unsigned short* __restrict__ gu,
                           unsigned short* __restrict__ act) {
  const int id = blockIdx.x * blockDim.x + threadIdx.x;  // TT*2*II/8 threads
  const int r = id >> 8;          // II/8 = 256 chunks per row
  const int i8 = (id & 255) * 8;
  short8 g8 = *(const short8*)(gu + (size_t)r * N1 + i8);
  short8 u8 = *(const short8*)(gu + (size_t)r * N1 + II + i8);
  short8 o;
#pragma unroll
  for (int j = 0; j < 8; j++) {
    float g = bf2f((unsigned short)g8[j]);
    float u = bf2f((unsigned short)u8[j]);
    g = fminf(g, LIMIT);
    u = fminf(fmaxf(u, -LIMIT), LIMIT);
    const float glu = g / (1.f + expf(-g * ALPHA));
    o[j] = f2bf((u + 1.f) * glu);
  }
  *(short8*)(act + (size_t)r * II + i8) = o;
}

// ---------------- GEMM2: act (bf16) x down_proj[e] -> dout (f32), split-K=2 ----
// blockIdx.z = e*2 + kchunk. Chunk 0 adds bias; combine sums both chunks.
__global__ __launch_bounds__(512, 4) void gemm_down(
    const unsigned short* __restrict__ act, const float* __restrict__ dp,
    const float* __restrict__ db, const int* __restrict__ counts,
    const int* __restrict__ rows, float* __restrict__ dout0,
    float* __restrict__ dout1) {
  const int e = blockIdx.z >> 1, kc = blockIdx.z & 1;
  const int mtile = blockIdx.y, ntile = blockIdx.x;
  const int count = counts[e];
  if (mtile * 128 >= count) return;
  const int kb = kc * (II / 2);  // 1024-wide K chunk
  const int* rl = rows + e * TT + mtile * 128;
  __shared__ short As[128][40];
  __shared__ short Bs[128][40];
  const int tid = threadIdx.x;
  const int lane = tid & 63, wave = tid >> 6;
  const int wm = (wave & 1) << 6, wn = (wave >> 1) << 5;
  const int quad = lane >> 4, r16 = lane & 15;

  const int arow = tid >> 2, akoct = tid & 3;
  const int cr = (mtile * 128 + arow < count) ? arow : (count - 1 - mtile * 128);
  const unsigned short* ap = act + (size_t)rl[cr] * II + kb + akoct * 8;

  const int bn = tid & 127, bko = tid >> 7;
  const float* bp = dp + (size_t)e * II * HH + (size_t)(kb + bko * 8) * HH + ntile * 128 + bn;

  floatx4 acc[4][2] = {};

  // prologue
  short8 va = *(const short8*)ap;
  float vb[8];
#pragma unroll
  for (int j = 0; j < 8; j++) vb[j] = bp[(size_t)j * HH];
  ap += 32;
  bp += (size_t)32 * HH;

  for (int k0 = 0; k0 < II / 2; k0 += 32) {
    __syncthreads();
    uintx4 bw;
    bw[0] = cvt2(vb[0], vb[1]); bw[1] = cvt2(vb[2], vb[3]);
    bw[2] = cvt2(vb[4], vb[5]); bw[3] = cvt2(vb[6], vb[7]);
    *(short8*)&As[arow][akoct * 8] = va;
    *(uintx4*)&Bs[bn][bko * 8] = bw;
    if (k0 + 32 < II / 2) {
      va = *(const short8*)ap;
#pragma unroll
      for (int j = 0; j < 8; j++) vb[j] = bp[(size_t)j * HH];
      ap += 32;
      bp += (size_t)32 * HH;
    }
    __syncthreads();
    short8 af[4], bf_[2];
#pragma unroll
    for (int i = 0; i < 4; i++)
      af[i] = *(const short8*)&As[wm + i * 16 + r16][quad * 8];
#pragma unroll
    for (int j = 0; j < 2; j++)
      bf_[j] = *(const short8*)&Bs[wn + j * 16 + r16][quad * 8];
#pragma unroll
    for (int i = 0; i < 4; i++)
#pragma unroll
      for (int j = 0; j < 2; j++)
        acc[i][j] = __builtin_amdgcn_mfma_f32_16x16x32_bf16(af[i], bf_[j], acc[i][j], 0, 0, 0);
  }
  float* dc = kc ? dout1 : dout0;
#pragma unroll
  for (int i = 0; i < 4; i++) {
#pragma unroll
    for (int reg = 0; reg < 4; reg++) {
      const int rrow = wm + i * 16 + quad * 4 + reg;
      if (mtile * 128 + rrow < count) {
        const int ent = rl[rrow];
        float* orow = dc + (size_t)ent * HH + ntile * 128;
#pragma unroll
        for (int j = 0; j < 2; j++) {
          const int c = wn + j * 16 + r16;
          float v = acc[i][j][reg];
          if (kc == 0) v += db[e * HH + ntile * 128 + c];
          orow[c] = v;
        }
      }
    }
  }
}

// ---------------- combine: out = w0*(d0a+d1a) + w1*(d0b+d1b) ----------------
__global__ void combine_kernel(const float* __restrict__ d0,
                               const float* __restrict__ d1,
                               const float* __restrict__ tw,
                               float* __restrict__ out) {
  const int id = blockIdx.x * blockDim.x + threadIdx.x;
  const int t = id >> 8;            // H/4 = 256 float4 per token
  const int h = (id & 255) * 4;
  const float w0 = tw[t * 2], w1 = tw[t * 2 + 1];
  const size_t r0 = (size_t)(2 * t) * HH + h;
  const size_t r1 = (size_t)(2 * t + 1) * HH + h;
  const float4 a0 = *(const float4*)(d0 + r0);
  const float4 a1 = *(const float4*)(d1 + r0);
  const float4 b0 = *(const float4*)(d0 + r1);
  const float4 b1 = *(const float4*)(d1 + r1);
  float4 o;
  o.x = w0 * (a0.x + a1.x) + w1 * (b0.x + b1.x);
  o.y = w0 * (a0.y + a1.y) + w1 * (b0.y + b1.y);
  o.z = w0 * (a0.z + a1.z) + w1 * (b0.z + b1.z);
  o.w = w0 * (a0.w + a1.w) + w1 * (b0.w + b1.w);
  *(float4*)(out + (size_t)t * HH + h) = o;
}

extern "C" void kernel_launch(void* const* d_in, const int* in_sizes, int n_in,
                              void* d_out, int out_size, void* d_ws, size_t ws_size,
                              hipStream_t stream) {
  const float* x   = (const float*)d_in[0];
  const float* rw  = (const float*)d_in[1];
  const float* rb  = (const float*)d_in[2];
  const float* gup = (const float*)d_in[3];
  const float* gub = (const float*)d_in[4];
  const float* dp  = (const float*)d_in[5];
  const float* db  = (const float*)d_in[6];
  float* out = (float*)d_out;

  char* ws = (char*)d_ws;
  int*   topk_idx = (int*)(ws + 0);                       // 16 KB
  float* topk_w   = (float*)(ws + 16384);                 // 16 KB
  int*   counts   = (int*)(ws + 32768);                   // 256 B
  int*   rows     = (int*)(ws + 33024);                   // 64 KB
  unsigned short* gu  = (unsigned short*)(ws + 131072);               // 33.5 MB
  unsigned short* act = (unsigned short*)(ws + 131072 + 33554432);    // 16.8 MB
  float* dout0 = (float*)(ws + 131072 + 33554432 + 16777216);         // 16.8 MB
  float* dout1 = (float*)(ws + 131072);  // aliases gu (dead after act_kernel)

  router_kernel<<<TT, 256, 0, stream>>>(x, rw, rb, topk_idx, topk_w);
  hipMemsetAsync(counts, 0, 64, stream);
  assign_kernel<<<(TT * 2 + 255) / 256, 256, 0, stream>>>(topk_idx, counts, rows);
  gemm_gu<<<dim3(N1 / 128, TT / 128, EE), 512, 0, stream>>>(x, gup, gub, counts, rows, gu);
  act_kernel<<<(TT * 2 * II / 8) / 256, 256, 0, stream>>>(gu, act);
  gemm_down<<<dim3(HH / 128, TT / 128, EE * 2), 512, 0, stream>>>(act, dp, db, counts, rows, dout0, dout1);
  combine_kernel<<<(TT * HH / 4) / 256, 256, 0, stream>>>(dout0, dout1, topk_w, out);
}